// Round 11
// baseline (694.370 us; speedup 1.0000x reference)
//
#include <hip/hip_runtime.h>
#include <hip/hip_bf16.h>
#include <math.h>

#define N_NODES 50000
#define N_EDGES 250000
#define BB      128
#define DD      302
#define QQ      600
#define CC      2000
#define NEG_SLOPE 0.2f
#define GS      304        // padded row stride for G and P (16B-aligned rows)
#define KP      320        // padded K (10 x 32)
#define KSTEPS  10         // KP / 32
#define PC      64         // nodes per pooling chunk
#define BPK_KS  20480      // shorts per k-step in packed B: [hi 320x32][lo 320x32]

typedef __attribute__((ext_vector_type(8))) short short8;
typedef __attribute__((ext_vector_type(4))) float f32x4;

__device__ __forceinline__ void gload_lds16(const void* g, void* l) {
    __builtin_amdgcn_global_load_lds((const __attribute__((address_space(1))) void*)g,
                                     (__attribute__((address_space(3))) void*)l, 16, 0, 0);
}

// bank-spread slot for packed B: 2 lanes/bank on ds_read_b128 (free per m136)
__device__ __host__ __forceinline__ int bswz(int q, int n) {
    return q ^ (n & 3) ^ ((n >> 2) & 3);
}

__device__ __forceinline__ unsigned short f2bf(float v) {   // round-half-up bf16
    return (unsigned short)((__float_as_uint(v) + 0x8000u) >> 16);
}
__device__ __forceinline__ float bf2f(unsigned short u) {
    return __uint_as_float(((unsigned int)u) << 16);
}

// ---------------------------------------------------------------- CSR build
// deg = pure in-edge histogram; self-loop slot is implicit:
// node n owns esrc slots [offs[n]+partials[n>>8]+n, ... + deg[n]] (deg[n]+1 slots).
__global__ void k_zero_dc(int* deg, int* cursor) {
    int i = blockIdx.x * 256 + threadIdx.x;
    if (i < N_NODES) { deg[i] = 0; cursor[i] = 0; }
}

__global__ void k_histogram(const int* __restrict__ dst, int* deg) {
    int e = blockIdx.x * blockDim.x + threadIdx.x;
    if (e < N_EDGES) atomicAdd(&deg[dst[e]], 1);
}

__global__ void k_scan_block(const int* __restrict__ deg, int* offs, int* partials) {
    __shared__ int sh[256];
    int i = blockIdx.x * 256 + threadIdx.x;
    int v = (i < N_NODES) ? deg[i] : 0;
    sh[threadIdx.x] = v;
    __syncthreads();
    for (int d = 1; d < 256; d <<= 1) {
        int t = (threadIdx.x >= d) ? sh[threadIdx.x - d] : 0;
        __syncthreads();
        sh[threadIdx.x] += t;
        __syncthreads();
    }
    if (i < N_NODES) offs[i] = sh[threadIdx.x] - v;   // exclusive (block-local)
    if (threadIdx.x == 255) partials[blockIdx.x] = sh[255];
}

__global__ void k_scan_partials(int* partials, int nb) {
    __shared__ int sh[256];
    int v = (threadIdx.x < nb) ? partials[threadIdx.x] : 0;
    sh[threadIdx.x] = v;
    __syncthreads();
    for (int d = 1; d < 256; d <<= 1) {
        int t = (threadIdx.x >= d) ? sh[threadIdx.x - d] : 0;
        __syncthreads();
        sh[threadIdx.x] += t;
        __syncthreads();
    }
    if (threadIdx.x < nb) partials[threadIdx.x] = sh[threadIdx.x] - v;  // exclusive
}

__global__ void k_scatter(const int* __restrict__ src, const int* __restrict__ dst,
                          const int* __restrict__ offs, const int* __restrict__ partials,
                          const int* __restrict__ deg, int* cursor, int* esrc) {
    int i = blockIdx.x * blockDim.x + threadIdx.x;
    if (i < N_EDGES) {
        int d = dst[i];
        int base = offs[d] + partials[d >> 8] + d;
        int pos = base + atomicAdd(&cursor[d], 1);
        esrc[pos] = src[i];
    } else if (i < N_EDGES + N_NODES) {
        int n = i - N_EDGES;
        int base = offs[n] + partials[n >> 8] + n;
        esrc[base + deg[n]] = n;   // self loop in the last slot (deg final before this kernel)
    }
}

// ---------------------------------------------------------------- theta pack + attvec rows + qp (one dispatch)
__global__ void k_theta_qp(const float* __restrict__ theta,
                           const float* __restrict__ att_src,
                           const float* __restrict__ att_dst,
                           unsigned short* __restrict__ bpk,
                           const float* __restrict__ query,
                           const float* __restrict__ attW,
                           float* __restrict__ qp) {
    if (blockIdx.x >= 402) {                          // ---- qp branch
        int t = blockIdx.x - 402;                     // 0..255
        int b = t >> 1;
        int d = (t & 1) * 256 + threadIdx.x;
        if (d >= DD) return;
        const float* qrow = query + (size_t)b * QQ;
        float acc = 0.f;
        #pragma unroll 8
        for (int q = 0; q < QQ; q++) acc += qrow[q] * attW[(size_t)q * DD + d];
        qp[(size_t)b * DD + d] = acc;
        return;
    }
    if (blockIdx.x >= 400) {
        int k = (blockIdx.x - 400) * 256 + threadIdx.x;
        if (k >= KP) return;
        float vs = 0.f, vd = 0.f;
        if (k < DD) {
            for (int j = 0; j < DD; j++) {
                float t = theta[j * DD + k];
                vs += t * att_src[j];
                vd += t * att_dst[j];
            }
        }
        int ks = k >> 5, kk = k & 31, q = kk >> 3, kb = kk & 7;
        size_t b0 = (size_t)ks * BPK_KS + DD * 32 + bswz(q, DD) * 8 + kb;
        size_t b1 = (size_t)ks * BPK_KS + (DD + 1) * 32 + bswz(q, DD + 1) * 8 + kb;
        unsigned int u, uh, ul;
        u  = __float_as_uint(vs);
        uh = (u + 0x8000u) & 0xffff0000u;
        ul = (__float_as_uint(vs - __uint_as_float(uh)) + 0x8000u) >> 16;
        bpk[b0]         = (unsigned short)(uh >> 16);
        bpk[b0 + 10240] = (unsigned short)ul;
        u  = __float_as_uint(vd);
        uh = (u + 0x8000u) & 0xffff0000u;
        ul = (__float_as_uint(vd - __uint_as_float(uh)) + 0x8000u) >> 16;
        bpk[b1]         = (unsigned short)(uh >> 16);
        bpk[b1 + 10240] = (unsigned short)ul;
        return;
    }
    int idx = blockIdx.x * 256 + threadIdx.x;
    if (idx >= KP * KP) return;
    int n = idx / KP, k = idx % KP;
    if (n == DD || n == DD + 1) return;
    float v = (n < DD && k < DD) ? theta[n * DD + k] : 0.f;
    unsigned int u  = __float_as_uint(v);
    unsigned int uh = (u + 0x8000u) & 0xffff0000u;    // round-half-up bf16
    float hf = __uint_as_float(uh);
    float lo = v - hf;
    unsigned int ul = (__float_as_uint(lo) + 0x8000u) >> 16;
    int ks = k >> 5, kk = k & 31, q = kk >> 3, kb = kk & 7;
    size_t base = (size_t)ks * BPK_KS + n * 32 + bswz(q, n) * 8 + kb;
    bpk[base]         = (unsigned short)(uh >> 16);
    bpk[base + 10240] = (unsigned short)ul;
}

// ---------------------------------------------------------------- split-bf16 MFMA GEMM
// A32 path (layer 1): fp32 A, hi/lo split, 3 MFMA passes.
// A16 path (layers 2-3): A is ALREADY bf16 (P stored bf16) -> al == 0 exactly,
// so the al*bh pass and the split-convert chain vanish (60->40 MFMA/k-step)
// and A-load bytes halve.  B-side hi/lo (theta precision) kept in both paths.
__global__ __launch_bounds__(256) void k_mfma_gemm(const float* __restrict__ A32,
                                                   const unsigned short* __restrict__ A16,
                                                   int lda,
                                                   const unsigned short* __restrict__ Bpk,
                                                   unsigned short* __restrict__ Gb,
                                                   float* __restrict__ a_s,
                                                   float* __restrict__ a_d, int M) {
    __shared__ __attribute__((aligned(16))) unsigned short Bs[2][BPK_KS]; // 80KB

    const int tid   = threadIdx.x;
    const int lane  = tid & 63;
    const int wave  = tid >> 6;         // 0..3
    const int q     = lane >> 4;        // 0..3
    const int mr    = lane & 15;
    const int m0    = blockIdx.x * 64;
    const int nbase = wave * 80;
    const bool abf  = (A16 != nullptr);

    f32x4 acc[4][5];
    #pragma unroll
    for (int i = 0; i < 4; i++)
        #pragma unroll
        for (int j = 0; j < 5; j++)
            acc[i][j] = (f32x4){0.f, 0.f, 0.f, 0.f};

    const float* arow32[4];
    const unsigned short* arow16[4];
    bool rok[4];
    #pragma unroll
    for (int mt = 0; mt < 4; mt++) {
        int row = m0 + mt * 16 + mr;
        rok[mt] = row < M;
        int r = row < M ? row : 0;
        arow32[mt] = abf ? nullptr : (A32 + (size_t)r * lda);
        arow16[mt] = abf ? (A16 + (size_t)r * GS) : nullptr;
    }

    const char* gB = (const char*)Bpk;

    auto loadA32 = [&](float (&f)[4][8], int ks) {
        const int k0c = ks * 32 + q * 8;
        #pragma unroll
        for (int mt = 0; mt < 4; mt++) {
            if (rok[mt] && (k0c + 8 <= DD)) {        // lda==DD only on layer 1
                float4 v0 = *(const float4*)(arow32[mt] + k0c);
                float4 v1 = *(const float4*)(arow32[mt] + k0c + 4);
                f[mt][0]=v0.x; f[mt][1]=v0.y; f[mt][2]=v0.z; f[mt][3]=v0.w;
                f[mt][4]=v1.x; f[mt][5]=v1.y; f[mt][6]=v1.z; f[mt][7]=v1.w;
            } else {
                #pragma unroll
                for (int p = 0; p < 8; p += 2) {
                    int k = k0c + p;
                    float2 t = {0.f, 0.f};
                    if (rok[mt] && k < DD) t = *(const float2*)(arow32[mt] + k);  // DD even
                    f[mt][p] = t.x; f[mt][p+1] = t.y;
                }
            }
        }
    };

    auto loadA16 = [&](short8 (&s)[4], int ks) {
        const int k0c = ks * 32 + q * 8;
        #pragma unroll
        for (int mt = 0; mt < 4; mt++) {
            if (rok[mt] && (k0c + 8 <= GS)) {        // P rows: 304 shorts, pads zero
                s[mt] = *(const short8*)(arow16[mt] + k0c);
            } else {
                s[mt] = (short8){0,0,0,0,0,0,0,0};
            }
        }
    };

    auto stageB = [&](int buf, int ks) {
        const char* gsrc = gB + (size_t)(ks * BPK_KS) * 2;
        #pragma unroll
        for (int j = 0; j < 10; j++) {
            int chunk = j * 4 + wave;                 // 0..39, wave-uniform base
            gload_lds16(gsrc + chunk * 1024 + lane * 16,
                        (char*)Bs[buf] + chunk * 1024);
        }
    };

    float fcur[4][8], fnext[4][8];
    short8 scur[4], snext[4];

    if (abf) loadA16(scur, 0); else loadA32(fcur, 0);
    stageB(0, 0);
    __syncthreads();

    #pragma unroll
    for (int ks = 0; ks < KSTEPS; ks++) {
        if (ks + 1 < KSTEPS) {
            stageB((ks + 1) & 1, ks + 1);
            if (abf) loadA16(snext, ks + 1); else loadA32(fnext, ks + 1);
        }

        short8 ah[4], al[4];
        if (abf) {
            #pragma unroll
            for (int mt = 0; mt < 4; mt++) ah[mt] = scur[mt];
        } else {
            #pragma unroll
            for (int mt = 0; mt < 4; mt++) {
                #pragma unroll
                for (int p = 0; p < 8; p++) {
                    unsigned int u  = __float_as_uint(fcur[mt][p]);
                    unsigned int uh = (u + 0x8000u) & 0xffff0000u;   // round-half-up bf16
                    float l = fcur[mt][p] - __uint_as_float(uh);
                    ah[mt][p] = (short)(uh >> 16);
                    al[mt][p] = (short)((__float_as_uint(l) + 0x8000u) >> 16);
                }
            }
        }

        const unsigned short* Bc = Bs[ks & 1];
        short8 bh[5], bl[5];
        #pragma unroll
        for (int nt = 0; nt < 5; nt++) {
            int col = nbase + nt * 16 + mr;
            int off = col * 32 + bswz(q, col) * 8;
            bh[nt] = *(const short8*)&Bc[off];
            bl[nt] = *(const short8*)&Bc[10240 + off];
        }
        #pragma unroll
        for (int nt = 0; nt < 5; nt++) {
            #pragma unroll
            for (int mt = 0; mt < 4; mt++) {
                acc[mt][nt] = __builtin_amdgcn_mfma_f32_16x16x32_bf16(ah[mt], bh[nt], acc[mt][nt], 0, 0, 0);
                acc[mt][nt] = __builtin_amdgcn_mfma_f32_16x16x32_bf16(ah[mt], bl[nt], acc[mt][nt], 0, 0, 0);
                if (!abf)
                    acc[mt][nt] = __builtin_amdgcn_mfma_f32_16x16x32_bf16(al[mt], bh[nt], acc[mt][nt], 0, 0, 0);
            }
        }

        __syncthreads();

        if (abf) {
            #pragma unroll
            for (int mt = 0; mt < 4; mt++) scur[mt] = snext[mt];
        } else {
            #pragma unroll
            for (int mt = 0; mt < 4; mt++)
                #pragma unroll
                for (int p = 0; p < 8; p++)
                    fcur[mt][p] = fnext[mt][p];
        }
    }

    // epilogue: C/D layout col=lane&15, row=(lane>>4)*4+reg; bf16 store, pads zeroed
    #pragma unroll
    for (int mt = 0; mt < 4; mt++) {
        int row_b = m0 + mt * 16 + q * 4;
        #pragma unroll
        for (int nt = 0; nt < 5; nt++) {
            int col = nbase + nt * 16 + mr;
            if (col > DD + 1) continue;
            #pragma unroll
            for (int r = 0; r < 4; r++) {
                int row = row_b + r;
                if (row >= M) continue;
                float v = acc[mt][nt][r];
                if (col < DD) {
                    Gb[(size_t)row * GS + col] = f2bf(v);
                } else if (col == DD) {
                    a_s[row] = v;
                    Gb[(size_t)row * GS + DD] = 0;        // keep pad col zero
                } else {
                    a_d[row] = v;
                    Gb[(size_t)row * GS + DD + 1] = 0;    // keep pad col zero
                }
            }
        }
    }
}

// ---------------------------------------------------------------- tiled SGEMM (final linear)
#define BM 64
#define BN 64
#define BK 16
__global__ __launch_bounds__(256) void k_gemm_nt(const float* __restrict__ A,
                                                 const float* __restrict__ B,
                                                 float* __restrict__ C,
                                                 int M, int N, int K,
                                                 const float* __restrict__ bias,
                                                 int relu_a) {
    __shared__ float As[BK][BM + 4];
    __shared__ float Bs[BK][BN + 4];
    int m0 = blockIdx.y * BM;
    int n0 = blockIdx.x * BN;
    int tid = threadIdx.x;
    int tr = tid >> 4;
    int tc = tid & 15;
    float acc[4][4] = {};
    for (int k0 = 0; k0 < K; k0 += BK) {
        #pragma unroll
        for (int j = 0; j < 4; j++) {
            int e = tid + 256 * j;
            int r = e >> 4;
            int k = e & 15;
            int gk = k0 + k;
            int gm = m0 + r;
            float va = 0.f;
            if (gm < M && gk < K) va = A[(size_t)gm * K + gk];
            if (relu_a) va = fmaxf(va, 0.f);
            As[k][r] = va;
            int gn = n0 + r;
            float vb = 0.f;
            if (gn < N && gk < K) vb = B[(size_t)gn * K + gk];
            Bs[k][r] = vb;
        }
        __syncthreads();
        #pragma unroll
        for (int k = 0; k < BK; k++) {
            float a[4], b[4];
            #pragma unroll
            for (int i = 0; i < 4; i++) a[i] = As[k][tr * 4 + i];
            #pragma unroll
            for (int j = 0; j < 4; j++) b[j] = Bs[k][tc * 4 + j];
            #pragma unroll
            for (int i = 0; i < 4; i++)
                #pragma unroll
                for (int j = 0; j < 4; j++)
                    acc[i][j] += a[i] * b[j];
        }
        __syncthreads();
    }
    #pragma unroll
    for (int i = 0; i < 4; i++) {
        int gm = m0 + tr * 4 + i;
        if (gm >= M) continue;
        #pragma unroll
        for (int j = 0; j < 4; j++) {
            int gn = n0 + tc * 4 + j;
            if (gn < N) {
                float v = acc[i][j];
                if (bias) v += bias[gn];
                C[(size_t)gm * N + gn] = v;
            }
        }
    }
}

// ---------------------------------------------------------------- softmax-aggregate (wave / dst node)
// Lane-parallel edge precompute + __shfl broadcast gather (R10, verified).
// Output P now stored BF16 (halves the write; next GEMM consumes bf16 A).
__global__ __launch_bounds__(256) void k_aggregate(const unsigned short* __restrict__ Gb,
                                                   const float* __restrict__ a_s,
                                                   const float* __restrict__ a_d,
                                                   const int* __restrict__ offs,
                                                   const int* __restrict__ partials,
                                                   const int* __restrict__ deg,
                                                   const int* __restrict__ esrc,
                                                   const float* __restrict__ bias,
                                                   unsigned short* __restrict__ Pb,
                                                   const float* __restrict__ qp,
                                                   const int* __restrict__ batch,
                                                   float* __restrict__ sarr) {
    int gid = blockIdx.x * blockDim.x + threadIdx.x;
    int n = gid >> 6, lane = gid & 63;
    if (n >= N_NODES) return;
    int beg = offs[n] + partials[n >> 8] + n;
    int cnt = deg[n] + 1;
    float adn = a_d[n];

    // ---- lane-parallel first chunk: lane i owns edge i
    int   s_reg = 0;
    float e_reg = -1.0e30f;
    float m = -1.0e30f, den = 0.f;
    if (lane < cnt) {
        s_reg = esrc[beg + lane];
        float e = a_s[s_reg] + adn;
        e = (e > 0.f) ? e : NEG_SLOPE * e;
        e_reg = e;
        m = e; den = 1.f;                 // exp(e-e)=1
    }
    // rare extra chunks: online accumulate
    for (int i = 64 + lane; i < cnt; i += 64) {
        float e = a_s[esrc[beg + i]] + adn;
        e = (e > 0.f) ? e : NEG_SLOPE * e;
        float nm = fmaxf(m, e);
        den = den * __expf(m - nm) + __expf(e - nm);
        m = nm;
    }
    // butterfly combine (finite sentinel keeps exp args finite)
    for (int off = 32; off; off >>= 1) {
        float mo = __shfl_xor(m, off);
        float dn = __shfl_xor(den, off);
        float nm = fmaxf(m, mo);
        den = den * __expf(m - nm) + dn * __expf(mo - nm);
        m = nm;
    }
    float inv_den = 1.f / den;
    float w_reg = __expf(e_reg - m) * inv_den;   // valid for lane < min(cnt,64)

    const int c0 = lane * 8;            // 8 bf16 cols per lane; lanes 0..37 active
    const bool act = c0 < GS;
    float A8[8] = {0.f,0.f,0.f,0.f,0.f,0.f,0.f,0.f};
    const int nfirst = (cnt < 64) ? cnt : 64;
    #pragma unroll 4
    for (int j = 0; j < nfirst; j++) {
        int   s = __shfl(s_reg, j);      // register broadcast — no memory dep
        float w = __shfl(w_reg, j);
        if (act) {
            int4 v = *(const int4*)(Gb + (size_t)s * GS + c0);
            unsigned int u0 = (unsigned int)v.x, u1 = (unsigned int)v.y;
            unsigned int u2 = (unsigned int)v.z, u3 = (unsigned int)v.w;
            A8[0] += w * __uint_as_float(u0 << 16);
            A8[1] += w * __uint_as_float(u0 & 0xffff0000u);
            A8[2] += w * __uint_as_float(u1 << 16);
            A8[3] += w * __uint_as_float(u1 & 0xffff0000u);
            A8[4] += w * __uint_as_float(u2 << 16);
            A8[5] += w * __uint_as_float(u2 & 0xffff0000u);
            A8[6] += w * __uint_as_float(u3 << 16);
            A8[7] += w * __uint_as_float(u3 & 0xffff0000u);
        }
    }
    // rare overflow edges: serial recompute path
    for (int i = 64; i < cnt; i++) {
        int s = esrc[beg + i];
        float e = a_s[s] + adn;
        e = (e > 0.f) ? e : NEG_SLOPE * e;
        float w = __expf(e - m) * inv_den;
        if (act) {
            int4 v = *(const int4*)(Gb + (size_t)s * GS + c0);
            unsigned int u0 = (unsigned int)v.x, u1 = (unsigned int)v.y;
            unsigned int u2 = (unsigned int)v.z, u3 = (unsigned int)v.w;
            A8[0] += w * __uint_as_float(u0 << 16);
            A8[1] += w * __uint_as_float(u0 & 0xffff0000u);
            A8[2] += w * __uint_as_float(u1 << 16);
            A8[3] += w * __uint_as_float(u1 & 0xffff0000u);
            A8[4] += w * __uint_as_float(u2 << 16);
            A8[5] += w * __uint_as_float(u2 & 0xffff0000u);
            A8[6] += w * __uint_as_float(u3 << 16);
            A8[7] += w * __uint_as_float(u3 & 0xffff0000u);
        }
    }

    // ---- bias + ReLU + write P (bf16); pads 302/303 -> 0
    float o[8];
    if (act) {
        short8 wv;
        #pragma unroll
        for (int p = 0; p < 8; p++) {
            int col = c0 + p;
            float b = (col < DD) ? bias[col] : 0.f;
            o[p] = (col < DD) ? fmaxf(A8[p] + b, 0.f) : 0.f;
            wv[p] = (short)f2bf(o[p]);
        }
        *(short8*)(Pb + (size_t)n * GS + c0) = wv;
    }

    // ---- fused pooling score (layer 3 only)
    if (sarr) {
        float d = 0.f;
        if (act) {
            const float* qv = qp + (size_t)batch[n] * DD;
            #pragma unroll
            for (int p = 0; p < 8; p++) {
                int col = c0 + p;
                if (col < DD) d += o[p] * qv[col];
            }
        }
        for (int off = 32; off; off >>= 1) d += __shfl_xor(d, off);
        if (lane == 0) sarr[n] = d * 0.04082482904638630f;   // 1/sqrt(600)
    }
}

// ---------------------------------------------------------------- pooling pieces
// per-graph softmax stats; fused: inline bounds search, writes wn, zeros pooled[b]
__global__ __launch_bounds__(256) void k_gstats(const float* __restrict__ sarr,
                                                const int* __restrict__ batch,
                                                float* __restrict__ wn,
                                                float* __restrict__ pooled) {
    int b = blockIdx.x;
    int lo = 0, hi = N_NODES;
    while (lo < hi) { int mid = (lo + hi) >> 1; if (batch[mid] < b) lo = mid + 1; else hi = mid; }
    int beg = lo;
    hi = N_NODES;
    while (lo < hi) { int mid = (lo + hi) >> 1; if (batch[mid] < b + 1) lo = mid + 1; else hi = mid; }
    int cnt = lo - beg;

    __shared__ float red[256];
    float m = -INFINITY;
    for (int i = threadIdx.x; i < cnt; i += 256) m = fmaxf(m, sarr[beg + i]);
    red[threadIdx.x] = m;
    __syncthreads();
    for (int d = 128; d; d >>= 1) {
        if (threadIdx.x < d) red[threadIdx.x] = fmaxf(red[threadIdx.x], red[threadIdx.x + d]);
        __syncthreads();
    }
    m = red[0];
    __syncthreads();
    float den = 0.f;
    for (int i = threadIdx.x; i < cnt; i += 256) den += __expf(sarr[beg + i] - m);
    red[threadIdx.x] = den;
    __syncthreads();
    for (int d = 128; d; d >>= 1) {
        if (threadIdx.x < d) red[threadIdx.x] += red[threadIdx.x + d];
        __syncthreads();
    }
    float dinv = (cnt > 0) ? 1.f / red[0] : 0.f;
    for (int i = threadIdx.x; i < cnt; i += 256)
        wn[beg + i] = __expf(sarr[beg + i] - m) * dinv;
    for (int j = threadIdx.x; j < DD; j += 256)
        pooled[(size_t)b * DD + j] = 0.f;
}

// node-chunk-parallel weighted segment sum over bf16 P (batch sorted)
__global__ __launch_bounds__(256) void k_poolacc(const unsigned short* __restrict__ Pb,
                                                 const float* __restrict__ wn,
                                                 const int* __restrict__ batch,
                                                 float* __restrict__ pooled) {
    int c0 = blockIdx.x * PC;
    if (c0 >= N_NODES) return;
    int nmax = N_NODES - c0; if (nmax > PC) nmax = PC;
    __shared__ int   sb[PC];
    __shared__ float sw[PC];
    for (int i = threadIdx.x; i < nmax; i += 256) {
        sb[i] = batch[c0 + i];
        sw[i] = wn[c0 + i];
    }
    __syncthreads();
    int f0 = threadIdx.x, f1 = threadIdx.x + 256;
    float a0 = 0.f, a1 = 0.f;
    int g = sb[0];
    for (int i = 0; i < nmax; i++) {
        int bi = sb[i];
        if (bi != g) {                       // wave-uniform branch
            if (f0 < DD) atomicAdd(&pooled[(size_t)g * DD + f0], a0);
            if (f1 < DD) atomicAdd(&pooled[(size_t)g * DD + f1], a1);
            a0 = 0.f; a1 = 0.f; g = bi;
        }
        float w = sw[i];
        const unsigned short* row = Pb + (size_t)(c0 + i) * GS;
        if (f0 < DD) a0 += w * bf2f(row[f0]);
        if (f1 < DD) a1 += w * bf2f(row[f1]);
    }
    if (f0 < DD) atomicAdd(&pooled[(size_t)g * DD + f0], a0);
    if (f1 < DD) atomicAdd(&pooled[(size_t)g * DD + f1], a1);
}

// ---------------------------------------------------------------- launch
extern "C" void kernel_launch(void* const* d_in, const int* in_sizes, int n_in,
                              void* d_out, int out_size, void* d_ws, size_t ws_size,
                              hipStream_t stream) {
    const float* x        = (const float*)d_in[0];
    const int*   edges    = (const int*)d_in[1];   // [2, E]
    const float* query    = (const float*)d_in[2];
    const int*   batch    = (const int*)d_in[3];
    const float* theta    = (const float*)d_in[4];
    const float* att_src  = (const float*)d_in[5];
    const float* att_dst  = (const float*)d_in[6];
    const float* gat_bias = (const float*)d_in[7];
    const float* attW     = (const float*)d_in[8];
    const float* lin_w    = (const float*)d_in[9];
    const float* lin_b    = (const float*)d_in[10];
    float* out = (float*)d_out;

    char* ws = (char*)d_ws;
    size_t off = 0;
    auto alloc = [&](size_t bytes) -> void* {
        off = (off + 255) & ~(size_t)255;
        void* p = ws + off;
        off += bytes;
        return p;
    };

    unsigned short* Gb = (unsigned short*)alloc((size_t)N_NODES * GS * 2);  // gemm output (bf16)
    unsigned short* Pb = (unsigned short*)alloc((size_t)N_NODES * GS * 2);  // layer output (bf16)
    unsigned short* bpk = (unsigned short*)alloc((size_t)KSTEPS * BPK_KS * 2); // packed B, 409.6KB
    float* a_s  = (float*)alloc((size_t)N_NODES * 4);
    float* a_d  = (float*)alloc((size_t)N_NODES * 4);
    float* sarr = (float*)alloc((size_t)N_NODES * 4);
    float* wn   = (float*)alloc((size_t)N_NODES * 4);
    int* deg    = (int*)alloc((size_t)N_NODES * 4);
    int* cursor = (int*)alloc((size_t)N_NODES * 4);
    int* offs   = (int*)alloc((size_t)N_NODES * 4);
    int* esrc   = (int*)alloc((size_t)(N_EDGES + N_NODES) * 4);
    int* partials = (int*)alloc(256 * 4);
    float* qp   = (float*)alloc((size_t)BB * DD * 4);
    float* pooled = (float*)alloc((size_t)BB * DD * 4);

    const int* e_src = edges;
    const int* e_dst = edges + N_EDGES;

    const int NB_SCAN = (N_NODES + 255) / 256;   // 196

    // ---- CSR build (deg/cursor zeroed via kernel; self-loop slot implicit)
    k_zero_dc<<<NB_SCAN, 256, 0, stream>>>(deg, cursor);
    k_histogram<<<(N_EDGES + 255) / 256, 256, 0, stream>>>(e_dst, deg);
    k_scan_block<<<NB_SCAN, 256, 0, stream>>>(deg, offs, partials);
    k_scan_partials<<<1, 256, 0, stream>>>(partials, NB_SCAN);
    k_scatter<<<(N_EDGES + N_NODES + 255) / 256, 256, 0, stream>>>(e_src, e_dst, offs, partials, deg, cursor, esrc);

    // ---- theta hi/lo split + attvec rows + qp (one fused dispatch)
    k_theta_qp<<<658, 256, 0, stream>>>(theta, att_src, att_dst, bpk, query, attW, qp);

    // ---- 3 GAT layers (layer 1: fp32 A; layers 2-3: bf16 A; layer 3 fuses scores)
    int mfma_blocks = (N_NODES + 63) / 64;   // 782
    int wave_blocks = (N_NODES + 3) / 4;
    for (int layer = 0; layer < 3; layer++) {
        if (layer == 0)
            k_mfma_gemm<<<mfma_blocks, 256, 0, stream>>>(x, nullptr, DD, bpk, Gb, a_s, a_d, N_NODES);
        else
            k_mfma_gemm<<<mfma_blocks, 256, 0, stream>>>(nullptr, Pb, GS, bpk, Gb, a_s, a_d, N_NODES);
        bool last = (layer == 2);
        k_aggregate<<<wave_blocks, 256, 0, stream>>>(Gb, a_s, a_d, offs, partials, deg, esrc, gat_bias, Pb,
                                                     last ? qp : (const float*)nullptr,
                                                     last ? batch : (const int*)nullptr,
                                                     last ? sarr : (float*)nullptr);
    }

    // ---- attention pooling + classifier
    k_gstats<<<BB, 256, 0, stream>>>(sarr, batch, wn, pooled);
    k_poolacc<<<(N_NODES + PC - 1) / PC, 256, 0, stream>>>(Pb, wn, batch, pooled);
    {
        dim3 g((CC + BN - 1) / BN, (BB + BM - 1) / BM);
        k_gemm_nt<<<g, 256, 0, stream>>>(pooled, lin_w, out, BB, CC, DD, lin_b, 1);
    }
}

// Round 12
// 644.382 us; speedup vs baseline: 1.0776x; 1.0776x over previous
//
#include <hip/hip_runtime.h>
#include <hip/hip_bf16.h>
#include <math.h>

#define N_NODES 50000
#define N_EDGES 250000
#define BB      128
#define DD      302
#define QQ      600
#define CC      2000
#define NEG_SLOPE 0.2f
#define GS      304        // padded row stride for G and P (16B-aligned rows)
#define KP      320        // padded K (10 x 32)
#define KSTEPS  10         // KP / 32
#define PC      64         // nodes per pooling chunk
#define BPK_KS  20480      // shorts per k-step in packed B: [hi 320x32][lo 320x32]

typedef __attribute__((ext_vector_type(8))) short short8;
typedef __attribute__((ext_vector_type(4))) float f32x4;

__device__ __forceinline__ void gload_lds16(const void* g, void* l) {
    __builtin_amdgcn_global_load_lds((const __attribute__((address_space(1))) void*)g,
                                     (__attribute__((address_space(3))) void*)l, 16, 0, 0);
}

// bank-spread slot for packed B: 2 lanes/bank on ds_read_b128 (free per m136)
__device__ __host__ __forceinline__ int bswz(int q, int n) {
    return q ^ (n & 3) ^ ((n >> 2) & 3);
}

__device__ __forceinline__ unsigned short f2bf(float v) {   // round-half-up bf16
    return (unsigned short)((__float_as_uint(v) + 0x8000u) >> 16);
}
__device__ __forceinline__ float bf2f(unsigned short u) {
    return __uint_as_float(((unsigned int)u) << 16);
}

// ---------------------------------------------------------------- CSR build
// deg = pure in-edge histogram; self-loop slot is implicit:
// node n owns esrc slots [offs[n]+partials[n>>8]+n, ... + deg[n]] (deg[n]+1 slots).
__global__ void k_zero_dc(int* deg, int* cursor) {
    int i = blockIdx.x * 256 + threadIdx.x;
    if (i < N_NODES) { deg[i] = 0; cursor[i] = 0; }
}

__global__ void k_histogram(const int* __restrict__ dst, int* deg) {
    int e = blockIdx.x * blockDim.x + threadIdx.x;
    if (e < N_EDGES) atomicAdd(&deg[dst[e]], 1);
}

__global__ void k_scan_block(const int* __restrict__ deg, int* offs, int* partials) {
    __shared__ int sh[256];
    int i = blockIdx.x * 256 + threadIdx.x;
    int v = (i < N_NODES) ? deg[i] : 0;
    sh[threadIdx.x] = v;
    __syncthreads();
    for (int d = 1; d < 256; d <<= 1) {
        int t = (threadIdx.x >= d) ? sh[threadIdx.x - d] : 0;
        __syncthreads();
        sh[threadIdx.x] += t;
        __syncthreads();
    }
    if (i < N_NODES) offs[i] = sh[threadIdx.x] - v;   // exclusive (block-local)
    if (threadIdx.x == 255) partials[blockIdx.x] = sh[255];
}

__global__ void k_scan_partials(int* partials, int nb) {
    __shared__ int sh[256];
    int v = (threadIdx.x < nb) ? partials[threadIdx.x] : 0;
    sh[threadIdx.x] = v;
    __syncthreads();
    for (int d = 1; d < 256; d <<= 1) {
        int t = (threadIdx.x >= d) ? sh[threadIdx.x - d] : 0;
        __syncthreads();
        sh[threadIdx.x] += t;
        __syncthreads();
    }
    if (threadIdx.x < nb) partials[threadIdx.x] = sh[threadIdx.x] - v;  // exclusive
}

__global__ void k_scatter(const int* __restrict__ src, const int* __restrict__ dst,
                          const int* __restrict__ offs, const int* __restrict__ partials,
                          const int* __restrict__ deg, int* cursor, int* esrc) {
    int i = blockIdx.x * blockDim.x + threadIdx.x;
    if (i < N_EDGES) {
        int d = dst[i];
        int base = offs[d] + partials[d >> 8] + d;
        int pos = base + atomicAdd(&cursor[d], 1);
        esrc[pos] = src[i];
    } else if (i < N_EDGES + N_NODES) {
        int n = i - N_EDGES;
        int base = offs[n] + partials[n >> 8] + n;
        esrc[base + deg[n]] = n;   // self loop in the last slot (deg final before this kernel)
    }
}

// ---------------------------------------------------------------- theta pack + attvec rows + qp (one dispatch)
__global__ void k_theta_qp(const float* __restrict__ theta,
                           const float* __restrict__ att_src,
                           const float* __restrict__ att_dst,
                           unsigned short* __restrict__ bpk,
                           const float* __restrict__ query,
                           const float* __restrict__ attW,
                           float* __restrict__ qp) {
    if (blockIdx.x >= 402) {                          // ---- qp branch
        int t = blockIdx.x - 402;                     // 0..255
        int b = t >> 1;
        int d = (t & 1) * 256 + threadIdx.x;
        if (d >= DD) return;
        const float* qrow = query + (size_t)b * QQ;
        float acc = 0.f;
        #pragma unroll 8
        for (int q = 0; q < QQ; q++) acc += qrow[q] * attW[(size_t)q * DD + d];
        qp[(size_t)b * DD + d] = acc;
        return;
    }
    if (blockIdx.x >= 400) {
        int k = (blockIdx.x - 400) * 256 + threadIdx.x;
        if (k >= KP) return;
        float vs = 0.f, vd = 0.f;
        if (k < DD) {
            for (int j = 0; j < DD; j++) {
                float t = theta[j * DD + k];
                vs += t * att_src[j];
                vd += t * att_dst[j];
            }
        }
        int ks = k >> 5, kk = k & 31, q = kk >> 3, kb = kk & 7;
        size_t b0 = (size_t)ks * BPK_KS + DD * 32 + bswz(q, DD) * 8 + kb;
        size_t b1 = (size_t)ks * BPK_KS + (DD + 1) * 32 + bswz(q, DD + 1) * 8 + kb;
        unsigned int u, uh, ul;
        u  = __float_as_uint(vs);
        uh = (u + 0x8000u) & 0xffff0000u;
        ul = (__float_as_uint(vs - __uint_as_float(uh)) + 0x8000u) >> 16;
        bpk[b0]         = (unsigned short)(uh >> 16);
        bpk[b0 + 10240] = (unsigned short)ul;
        u  = __float_as_uint(vd);
        uh = (u + 0x8000u) & 0xffff0000u;
        ul = (__float_as_uint(vd - __uint_as_float(uh)) + 0x8000u) >> 16;
        bpk[b1]         = (unsigned short)(uh >> 16);
        bpk[b1 + 10240] = (unsigned short)ul;
        return;
    }
    int idx = blockIdx.x * 256 + threadIdx.x;
    if (idx >= KP * KP) return;
    int n = idx / KP, k = idx % KP;
    if (n == DD || n == DD + 1) return;
    float v = (n < DD && k < DD) ? theta[n * DD + k] : 0.f;
    unsigned int u  = __float_as_uint(v);
    unsigned int uh = (u + 0x8000u) & 0xffff0000u;    // round-half-up bf16
    float hf = __uint_as_float(uh);
    float lo = v - hf;
    unsigned int ul = (__float_as_uint(lo) + 0x8000u) >> 16;
    int ks = k >> 5, kk = k & 31, q = kk >> 3, kb = kk & 7;
    size_t base = (size_t)ks * BPK_KS + n * 32 + bswz(q, n) * 8 + kb;
    bpk[base]         = (unsigned short)(uh >> 16);
    bpk[base + 10240] = (unsigned short)ul;
}

// ---------------------------------------------------------------- GEMM kernel 1: fp32 A (layer 1)
// R10-verified structure: hi/lo split A, 3 MFMA passes, bf16 C out.
__global__ __launch_bounds__(256) void k_mfma_gemm32(const float* __restrict__ A, int lda,
                                                     const unsigned short* __restrict__ Bpk,
                                                     unsigned short* __restrict__ Gb,
                                                     float* __restrict__ a_s,
                                                     float* __restrict__ a_d, int M) {
    __shared__ __attribute__((aligned(16))) unsigned short Bs[2][BPK_KS]; // 80KB

    const int tid   = threadIdx.x;
    const int lane  = tid & 63;
    const int wave  = tid >> 6;         // 0..3
    const int q     = lane >> 4;        // 0..3
    const int mr    = lane & 15;
    const int m0    = blockIdx.x * 64;
    const int nbase = wave * 80;

    f32x4 acc[4][5];
    #pragma unroll
    for (int i = 0; i < 4; i++)
        #pragma unroll
        for (int j = 0; j < 5; j++)
            acc[i][j] = (f32x4){0.f, 0.f, 0.f, 0.f};

    const float* arow[4];
    bool rok[4];
    #pragma unroll
    for (int mt = 0; mt < 4; mt++) {
        int row = m0 + mt * 16 + mr;
        rok[mt] = row < M;
        arow[mt] = A + (size_t)(row < M ? row : 0) * lda;
    }

    const char* gB = (const char*)Bpk;

    auto loadA = [&](float (&f)[4][8], int ks) {
        const int k0c = ks * 32 + q * 8;
        #pragma unroll
        for (int mt = 0; mt < 4; mt++) {
            if (rok[mt] && (k0c + 8 <= DD)) {
                float4 v0 = *(const float4*)(arow[mt] + k0c);
                float4 v1 = *(const float4*)(arow[mt] + k0c + 4);
                f[mt][0]=v0.x; f[mt][1]=v0.y; f[mt][2]=v0.z; f[mt][3]=v0.w;
                f[mt][4]=v1.x; f[mt][5]=v1.y; f[mt][6]=v1.z; f[mt][7]=v1.w;
            } else {
                #pragma unroll
                for (int p = 0; p < 8; p += 2) {
                    int k = k0c + p;
                    float2 t = {0.f, 0.f};
                    if (rok[mt] && k < DD) t = *(const float2*)(arow[mt] + k);  // DD even
                    f[mt][p] = t.x; f[mt][p+1] = t.y;
                }
            }
        }
    };

    auto stageB = [&](int buf, int ks) {
        const char* gsrc = gB + (size_t)(ks * BPK_KS) * 2;
        #pragma unroll
        for (int j = 0; j < 10; j++) {
            int chunk = j * 4 + wave;                 // 0..39, wave-uniform base
            gload_lds16(gsrc + chunk * 1024 + lane * 16,
                        (char*)Bs[buf] + chunk * 1024);
        }
    };

    float fcur[4][8], fnext[4][8];

    loadA(fcur, 0);
    stageB(0, 0);
    __syncthreads();

    #pragma unroll
    for (int ks = 0; ks < KSTEPS; ks++) {
        if (ks + 1 < KSTEPS) {
            stageB((ks + 1) & 1, ks + 1);
            loadA(fnext, ks + 1);
        }

        short8 ah[4], al[4];
        #pragma unroll
        for (int mt = 0; mt < 4; mt++) {
            #pragma unroll
            for (int p = 0; p < 8; p++) {
                unsigned int u  = __float_as_uint(fcur[mt][p]);
                unsigned int uh = (u + 0x8000u) & 0xffff0000u;   // round-half-up bf16
                float l = fcur[mt][p] - __uint_as_float(uh);
                ah[mt][p] = (short)(uh >> 16);
                al[mt][p] = (short)((__float_as_uint(l) + 0x8000u) >> 16);
            }
        }

        const unsigned short* Bc = Bs[ks & 1];
        short8 bh[5], bl[5];
        #pragma unroll
        for (int nt = 0; nt < 5; nt++) {
            int col = nbase + nt * 16 + mr;
            int off = col * 32 + bswz(q, col) * 8;
            bh[nt] = *(const short8*)&Bc[off];
            bl[nt] = *(const short8*)&Bc[10240 + off];
        }
        #pragma unroll
        for (int nt = 0; nt < 5; nt++) {
            #pragma unroll
            for (int mt = 0; mt < 4; mt++) {
                acc[mt][nt] = __builtin_amdgcn_mfma_f32_16x16x32_bf16(ah[mt], bh[nt], acc[mt][nt], 0, 0, 0);
                acc[mt][nt] = __builtin_amdgcn_mfma_f32_16x16x32_bf16(ah[mt], bl[nt], acc[mt][nt], 0, 0, 0);
                acc[mt][nt] = __builtin_amdgcn_mfma_f32_16x16x32_bf16(al[mt], bh[nt], acc[mt][nt], 0, 0, 0);
            }
        }

        __syncthreads();

        #pragma unroll
        for (int mt = 0; mt < 4; mt++)
            #pragma unroll
            for (int p = 0; p < 8; p++)
                fcur[mt][p] = fnext[mt][p];
    }

    #pragma unroll
    for (int mt = 0; mt < 4; mt++) {
        int row_b = m0 + mt * 16 + q * 4;
        #pragma unroll
        for (int nt = 0; nt < 5; nt++) {
            int col = nbase + nt * 16 + mr;
            if (col > DD + 1) continue;
            #pragma unroll
            for (int r = 0; r < 4; r++) {
                int row = row_b + r;
                if (row >= M) continue;
                float v = acc[mt][nt][r];
                if (col < DD) {
                    Gb[(size_t)row * GS + col] = f2bf(v);
                } else if (col == DD) {
                    a_s[row] = v;
                    Gb[(size_t)row * GS + DD] = 0;
                } else {
                    a_d[row] = v;
                    Gb[(size_t)row * GS + DD + 1] = 0;
                }
            }
        }
    }
}

// ---------------------------------------------------------------- GEMM kernel 2: bf16 A (layers 2-3)
// A(=P) exactly representable in bf16 -> lo(A)==0: no split chain, 2 MFMA
// passes (40/k-step vs 60), A-load bytes halved.  Own kernel = tight regalloc.
__global__ __launch_bounds__(256) void k_mfma_gemm16(const unsigned short* __restrict__ A,
                                                     const unsigned short* __restrict__ Bpk,
                                                     unsigned short* __restrict__ Gb,
                                                     float* __restrict__ a_s,
                                                     float* __restrict__ a_d, int M) {
    __shared__ __attribute__((aligned(16))) unsigned short Bs[2][BPK_KS]; // 80KB

    const int tid   = threadIdx.x;
    const int lane  = tid & 63;
    const int wave  = tid >> 6;         // 0..3
    const int q     = lane >> 4;        // 0..3
    const int mr    = lane & 15;
    const int m0    = blockIdx.x * 64;
    const int nbase = wave * 80;

    f32x4 acc[4][5];
    #pragma unroll
    for (int i = 0; i < 4; i++)
        #pragma unroll
        for (int j = 0; j < 5; j++)
            acc[i][j] = (f32x4){0.f, 0.f, 0.f, 0.f};

    const unsigned short* arow[4];
    bool rok[4];
    #pragma unroll
    for (int mt = 0; mt < 4; mt++) {
        int row = m0 + mt * 16 + mr;
        rok[mt] = row < M;
        arow[mt] = A + (size_t)(row < M ? row : 0) * GS;
    }

    const char* gB = (const char*)Bpk;

    auto loadA = [&](short8 (&s)[4], int ks) {
        const int k0c = ks * 32 + q * 8;
        #pragma unroll
        for (int mt = 0; mt < 4; mt++) {
            if (rok[mt] && (k0c + 8 <= GS)) {        // P rows: 304 shorts, pads zero
                s[mt] = *(const short8*)(arow[mt] + k0c);
            } else {
                s[mt] = (short8){0,0,0,0,0,0,0,0};   // k >= 304: zero (B pads also zero)
            }
        }
    };

    auto stageB = [&](int buf, int ks) {
        const char* gsrc = gB + (size_t)(ks * BPK_KS) * 2;
        #pragma unroll
        for (int j = 0; j < 10; j++) {
            int chunk = j * 4 + wave;                 // 0..39, wave-uniform base
            gload_lds16(gsrc + chunk * 1024 + lane * 16,
                        (char*)Bs[buf] + chunk * 1024);
        }
    };

    short8 scur[4], snext[4];

    loadA(scur, 0);
    stageB(0, 0);
    __syncthreads();

    #pragma unroll
    for (int ks = 0; ks < KSTEPS; ks++) {
        if (ks + 1 < KSTEPS) {
            stageB((ks + 1) & 1, ks + 1);
            loadA(snext, ks + 1);
        }

        const unsigned short* Bc = Bs[ks & 1];
        short8 bh[5], bl[5];
        #pragma unroll
        for (int nt = 0; nt < 5; nt++) {
            int col = nbase + nt * 16 + mr;
            int off = col * 32 + bswz(q, col) * 8;
            bh[nt] = *(const short8*)&Bc[off];
            bl[nt] = *(const short8*)&Bc[10240 + off];
        }
        #pragma unroll
        for (int nt = 0; nt < 5; nt++) {
            #pragma unroll
            for (int mt = 0; mt < 4; mt++) {
                acc[mt][nt] = __builtin_amdgcn_mfma_f32_16x16x32_bf16(scur[mt], bh[nt], acc[mt][nt], 0, 0, 0);
                acc[mt][nt] = __builtin_amdgcn_mfma_f32_16x16x32_bf16(scur[mt], bl[nt], acc[mt][nt], 0, 0, 0);
            }
        }

        __syncthreads();

        #pragma unroll
        for (int mt = 0; mt < 4; mt++) scur[mt] = snext[mt];
    }

    #pragma unroll
    for (int mt = 0; mt < 4; mt++) {
        int row_b = m0 + mt * 16 + q * 4;
        #pragma unroll
        for (int nt = 0; nt < 5; nt++) {
            int col = nbase + nt * 16 + mr;
            if (col > DD + 1) continue;
            #pragma unroll
            for (int r = 0; r < 4; r++) {
                int row = row_b + r;
                if (row >= M) continue;
                float v = acc[mt][nt][r];
                if (col < DD) {
                    Gb[(size_t)row * GS + col] = f2bf(v);
                } else if (col == DD) {
                    a_s[row] = v;
                    Gb[(size_t)row * GS + DD] = 0;
                } else {
                    a_d[row] = v;
                    Gb[(size_t)row * GS + DD + 1] = 0;
                }
            }
        }
    }
}

// ---------------------------------------------------------------- tiled SGEMM (final linear)
#define BM 64
#define BN 64
#define BK 16
__global__ __launch_bounds__(256) void k_gemm_nt(const float* __restrict__ A,
                                                 const float* __restrict__ B,
                                                 float* __restrict__ C,
                                                 int M, int N, int K,
                                                 const float* __restrict__ bias,
                                                 int relu_a) {
    __shared__ float As[BK][BM + 4];
    __shared__ float Bs[BK][BN + 4];
    int m0 = blockIdx.y * BM;
    int n0 = blockIdx.x * BN;
    int tid = threadIdx.x;
    int tr = tid >> 4;
    int tc = tid & 15;
    float acc[4][4] = {};
    for (int k0 = 0; k0 < K; k0 += BK) {
        #pragma unroll
        for (int j = 0; j < 4; j++) {
            int e = tid + 256 * j;
            int r = e >> 4;
            int k = e & 15;
            int gk = k0 + k;
            int gm = m0 + r;
            float va = 0.f;
            if (gm < M && gk < K) va = A[(size_t)gm * K + gk];
            if (relu_a) va = fmaxf(va, 0.f);
            As[k][r] = va;
            int gn = n0 + r;
            float vb = 0.f;
            if (gn < N && gk < K) vb = B[(size_t)gn * K + gk];
            Bs[k][r] = vb;
        }
        __syncthreads();
        #pragma unroll
        for (int k = 0; k < BK; k++) {
            float a[4], b[4];
            #pragma unroll
            for (int i = 0; i < 4; i++) a[i] = As[k][tr * 4 + i];
            #pragma unroll
            for (int j = 0; j < 4; j++) b[j] = Bs[k][tc * 4 + j];
            #pragma unroll
            for (int i = 0; i < 4; i++)
                #pragma unroll
                for (int j = 0; j < 4; j++)
                    acc[i][j] += a[i] * b[j];
        }
        __syncthreads();
    }
    #pragma unroll
    for (int i = 0; i < 4; i++) {
        int gm = m0 + tr * 4 + i;
        if (gm >= M) continue;
        #pragma unroll
        for (int j = 0; j < 4; j++) {
            int gn = n0 + tc * 4 + j;
            if (gn < N) {
                float v = acc[i][j];
                if (bias) v += bias[gn];
                C[(size_t)gm * N + gn] = v;
            }
        }
    }
}

// ---------------------------------------------------------------- softmax-aggregate (wave / dst node)
// Lane-parallel edge precompute + __shfl broadcast gather (R10, verified).
// Output P stored BF16 (halves the write; next GEMM consumes bf16 A).
__global__ __launch_bounds__(256) void k_aggregate(const unsigned short* __restrict__ Gb,
                                                   const float* __restrict__ a_s,
                                                   const float* __restrict__ a_d,
                                                   const int* __restrict__ offs,
                                                   const int* __restrict__ partials,
                                                   const int* __restrict__ deg,
                                                   const int* __restrict__ esrc,
                                                   const float* __restrict__ bias,
                                                   unsigned short* __restrict__ Pb,
                                                   const float* __restrict__ qp,
                                                   const int* __restrict__ batch,
                                                   float* __restrict__ sarr) {
    int gid = blockIdx.x * blockDim.x + threadIdx.x;
    int n = gid >> 6, lane = gid & 63;
    if (n >= N_NODES) return;
    int beg = offs[n] + partials[n >> 8] + n;
    int cnt = deg[n] + 1;
    float adn = a_d[n];

    // ---- lane-parallel first chunk: lane i owns edge i
    int   s_reg = 0;
    float e_reg = -1.0e30f;
    float m = -1.0e30f, den = 0.f;
    if (lane < cnt) {
        s_reg = esrc[beg + lane];
        float e = a_s[s_reg] + adn;
        e = (e > 0.f) ? e : NEG_SLOPE * e;
        e_reg = e;
        m = e; den = 1.f;                 // exp(e-e)=1
    }
    // rare extra chunks: online accumulate
    for (int i = 64 + lane; i < cnt; i += 64) {
        float e = a_s[esrc[beg + i]] + adn;
        e = (e > 0.f) ? e : NEG_SLOPE * e;
        float nm = fmaxf(m, e);
        den = den * __expf(m - nm) + __expf(e - nm);
        m = nm;
    }
    // butterfly combine (finite sentinel keeps exp args finite)
    for (int off = 32; off; off >>= 1) {
        float mo = __shfl_xor(m, off);
        float dn = __shfl_xor(den, off);
        float nm = fmaxf(m, mo);
        den = den * __expf(m - nm) + dn * __expf(mo - nm);
        m = nm;
    }
    float inv_den = 1.f / den;
    float w_reg = __expf(e_reg - m) * inv_den;   // valid for lane < min(cnt,64)

    const int c0 = lane * 8;            // 8 bf16 cols per lane; lanes 0..37 active
    const bool act = c0 < GS;
    float A8[8] = {0.f,0.f,0.f,0.f,0.f,0.f,0.f,0.f};
    const int nfirst = (cnt < 64) ? cnt : 64;
    #pragma unroll 4
    for (int j = 0; j < nfirst; j++) {
        int   s = __shfl(s_reg, j);      // register broadcast — no memory dep
        float w = __shfl(w_reg, j);
        if (act) {
            int4 v = *(const int4*)(Gb + (size_t)s * GS + c0);
            unsigned int u0 = (unsigned int)v.x, u1 = (unsigned int)v.y;
            unsigned int u2 = (unsigned int)v.z, u3 = (unsigned int)v.w;
            A8[0] += w * __uint_as_float(u0 << 16);
            A8[1] += w * __uint_as_float(u0 & 0xffff0000u);
            A8[2] += w * __uint_as_float(u1 << 16);
            A8[3] += w * __uint_as_float(u1 & 0xffff0000u);
            A8[4] += w * __uint_as_float(u2 << 16);
            A8[5] += w * __uint_as_float(u2 & 0xffff0000u);
            A8[6] += w * __uint_as_float(u3 << 16);
            A8[7] += w * __uint_as_float(u3 & 0xffff0000u);
        }
    }
    // rare overflow edges: serial recompute path
    for (int i = 64; i < cnt; i++) {
        int s = esrc[beg + i];
        float e = a_s[s] + adn;
        e = (e > 0.f) ? e : NEG_SLOPE * e;
        float w = __expf(e - m) * inv_den;
        if (act) {
            int4 v = *(const int4*)(Gb + (size_t)s * GS + c0);
            unsigned int u0 = (unsigned int)v.x, u1 = (unsigned int)v.y;
            unsigned int u2 = (unsigned int)v.z, u3 = (unsigned int)v.w;
            A8[0] += w * __uint_as_float(u0 << 16);
            A8[1] += w * __uint_as_float(u0 & 0xffff0000u);
            A8[2] += w * __uint_as_float(u1 << 16);
            A8[3] += w * __uint_as_float(u1 & 0xffff0000u);
            A8[4] += w * __uint_as_float(u2 << 16);
            A8[5] += w * __uint_as_float(u2 & 0xffff0000u);
            A8[6] += w * __uint_as_float(u3 << 16);
            A8[7] += w * __uint_as_float(u3 & 0xffff0000u);
        }
    }

    // ---- bias + ReLU + write P (bf16); pads 302/303 -> 0
    float o[8];
    if (act) {
        short8 wv;
        #pragma unroll
        for (int p = 0; p < 8; p++) {
            int col = c0 + p;
            float b = (col < DD) ? bias[col] : 0.f;
            o[p] = (col < DD) ? fmaxf(A8[p] + b, 0.f) : 0.f;
            wv[p] = (short)f2bf(o[p]);
        }
        *(short8*)(Pb + (size_t)n * GS + c0) = wv;
    }

    // ---- fused pooling score (layer 3 only)
    if (sarr) {
        float d = 0.f;
        if (act) {
            const float* qv = qp + (size_t)batch[n] * DD;
            #pragma unroll
            for (int p = 0; p < 8; p++) {
                int col = c0 + p;
                if (col < DD) d += o[p] * qv[col];
            }
        }
        for (int off = 32; off; off >>= 1) d += __shfl_xor(d, off);
        if (lane == 0) sarr[n] = d * 0.04082482904638630f;   // 1/sqrt(600)
    }
}

// ---------------------------------------------------------------- pooling pieces
// per-graph softmax stats; fused: inline bounds search, writes wn, zeros pooled[b]
__global__ __launch_bounds__(256) void k_gstats(const float* __restrict__ sarr,
                                                const int* __restrict__ batch,
                                                float* __restrict__ wn,
                                                float* __restrict__ pooled) {
    int b = blockIdx.x;
    int lo = 0, hi = N_NODES;
    while (lo < hi) { int mid = (lo + hi) >> 1; if (batch[mid] < b) lo = mid + 1; else hi = mid; }
    int beg = lo;
    hi = N_NODES;
    while (lo < hi) { int mid = (lo + hi) >> 1; if (batch[mid] < b + 1) lo = mid + 1; else hi = mid; }
    int cnt = lo - beg;

    __shared__ float red[256];
    float m = -INFINITY;
    for (int i = threadIdx.x; i < cnt; i += 256) m = fmaxf(m, sarr[beg + i]);
    red[threadIdx.x] = m;
    __syncthreads();
    for (int d = 128; d; d >>= 1) {
        if (threadIdx.x < d) red[threadIdx.x] = fmaxf(red[threadIdx.x], red[threadIdx.x + d]);
        __syncthreads();
    }
    m = red[0];
    __syncthreads();
    float den = 0.f;
    for (int i = threadIdx.x; i < cnt; i += 256) den += __expf(sarr[beg + i] - m);
    red[threadIdx.x] = den;
    __syncthreads();
    for (int d = 128; d; d >>= 1) {
        if (threadIdx.x < d) red[threadIdx.x] += red[threadIdx.x + d];
        __syncthreads();
    }
    float dinv = (cnt > 0) ? 1.f / red[0] : 0.f;
    for (int i = threadIdx.x; i < cnt; i += 256)
        wn[beg + i] = __expf(sarr[beg + i] - m) * dinv;
    for (int j = threadIdx.x; j < DD; j += 256)
        pooled[(size_t)b * DD + j] = 0.f;
}

// node-chunk-parallel weighted segment sum over bf16 P (batch sorted)
__global__ __launch_bounds__(256) void k_poolacc(const unsigned short* __restrict__ Pb,
                                                 const float* __restrict__ wn,
                                                 const int* __restrict__ batch,
                                                 float* __restrict__ pooled) {
    int c0 = blockIdx.x * PC;
    if (c0 >= N_NODES) return;
    int nmax = N_NODES - c0; if (nmax > PC) nmax = PC;
    __shared__ int   sb[PC];
    __shared__ float sw[PC];
    for (int i = threadIdx.x; i < nmax; i += 256) {
        sb[i] = batch[c0 + i];
        sw[i] = wn[c0 + i];
    }
    __syncthreads();
    int f0 = threadIdx.x, f1 = threadIdx.x + 256;
    float a0 = 0.f, a1 = 0.f;
    int g = sb[0];
    for (int i = 0; i < nmax; i++) {
        int bi = sb[i];
        if (bi != g) {                       // wave-uniform branch
            if (f0 < DD) atomicAdd(&pooled[(size_t)g * DD + f0], a0);
            if (f1 < DD) atomicAdd(&pooled[(size_t)g * DD + f1], a1);
            a0 = 0.f; a1 = 0.f; g = bi;
        }
        float w = sw[i];
        const unsigned short* row = Pb + (size_t)(c0 + i) * GS;
        if (f0 < DD) a0 += w * bf2f(row[f0]);
        if (f1 < DD) a1 += w * bf2f(row[f1]);
    }
    if (f0 < DD) atomicAdd(&pooled[(size_t)g * DD + f0], a0);
    if (f1 < DD) atomicAdd(&pooled[(size_t)g * DD + f1], a1);
}

// ---------------------------------------------------------------- launch
extern "C" void kernel_launch(void* const* d_in, const int* in_sizes, int n_in,
                              void* d_out, int out_size, void* d_ws, size_t ws_size,
                              hipStream_t stream) {
    const float* x        = (const float*)d_in[0];
    const int*   edges    = (const int*)d_in[1];   // [2, E]
    const float* query    = (const float*)d_in[2];
    const int*   batch    = (const int*)d_in[3];
    const float* theta    = (const float*)d_in[4];
    const float* att_src  = (const float*)d_in[5];
    const float* att_dst  = (const float*)d_in[6];
    const float* gat_bias = (const float*)d_in[7];
    const float* attW     = (const float*)d_in[8];
    const float* lin_w    = (const float*)d_in[9];
    const float* lin_b    = (const float*)d_in[10];
    float* out = (float*)d_out;

    char* ws = (char*)d_ws;
    size_t off = 0;
    auto alloc = [&](size_t bytes) -> void* {
        off = (off + 255) & ~(size_t)255;
        void* p = ws + off;
        off += bytes;
        return p;
    };

    unsigned short* Gb = (unsigned short*)alloc((size_t)N_NODES * GS * 2);  // gemm output (bf16)
    unsigned short* Pb = (unsigned short*)alloc((size_t)N_NODES * GS * 2);  // layer output (bf16)
    unsigned short* bpk = (unsigned short*)alloc((size_t)KSTEPS * BPK_KS * 2); // packed B, 409.6KB
    float* a_s  = (float*)alloc((size_t)N_NODES * 4);
    float* a_d  = (float*)alloc((size_t)N_NODES * 4);
    float* sarr = (float*)alloc((size_t)N_NODES * 4);
    float* wn   = (float*)alloc((size_t)N_NODES * 4);
    int* deg    = (int*)alloc((size_t)N_NODES * 4);
    int* cursor = (int*)alloc((size_t)N_NODES * 4);
    int* offs   = (int*)alloc((size_t)N_NODES * 4);
    int* esrc   = (int*)alloc((size_t)(N_EDGES + N_NODES) * 4);
    int* partials = (int*)alloc(256 * 4);
    float* qp   = (float*)alloc((size_t)BB * DD * 4);
    float* pooled = (float*)alloc((size_t)BB * DD * 4);

    const int* e_src = edges;
    const int* e_dst = edges + N_EDGES;

    const int NB_SCAN = (N_NODES + 255) / 256;   // 196

    // ---- CSR build (deg/cursor zeroed via kernel; self-loop slot implicit)
    k_zero_dc<<<NB_SCAN, 256, 0, stream>>>(deg, cursor);
    k_histogram<<<(N_EDGES + 255) / 256, 256, 0, stream>>>(e_dst, deg);
    k_scan_block<<<NB_SCAN, 256, 0, stream>>>(deg, offs, partials);
    k_scan_partials<<<1, 256, 0, stream>>>(partials, NB_SCAN);
    k_scatter<<<(N_EDGES + N_NODES + 255) / 256, 256, 0, stream>>>(e_src, e_dst, offs, partials, deg, cursor, esrc);

    // ---- theta hi/lo split + attvec rows + qp (one fused dispatch)
    k_theta_qp<<<658, 256, 0, stream>>>(theta, att_src, att_dst, bpk, query, attW, qp);

    // ---- 3 GAT layers (layer 1: fp32-A kernel; layers 2-3: bf16-A kernel)
    int mfma_blocks = (N_NODES + 63) / 64;   // 782
    int wave_blocks = (N_NODES + 3) / 4;
    for (int layer = 0; layer < 3; layer++) {
        if (layer == 0)
            k_mfma_gemm32<<<mfma_blocks, 256, 0, stream>>>(x, DD, bpk, Gb, a_s, a_d, N_NODES);
        else
            k_mfma_gemm16<<<mfma_blocks, 256, 0, stream>>>(Pb, bpk, Gb, a_s, a_d, N_NODES);
        bool last = (layer == 2);
        k_aggregate<<<wave_blocks, 256, 0, stream>>>(Gb, a_s, a_d, offs, partials, deg, esrc, gat_bias, Pb,
                                                     last ? qp : (const float*)nullptr,
                                                     last ? batch : (const int*)nullptr,
                                                     last ? sarr : (float*)nullptr);
    }

    // ---- attention pooling + classifier
    k_gstats<<<BB, 256, 0, stream>>>(sarr, batch, wn, pooled);
    k_poolacc<<<(N_NODES + PC - 1) / PC, 256, 0, stream>>>(Pb, wn, batch, pooled);
    {
        dim3 g((CC + BN - 1) / BN, (BB + BM - 1) / BM);
        k_gemm_nt<<<g, 256, 0, stream>>>(pooled, lin_w, out, BB, CC, DD, lin_b, 1);
    }
}

// Round 13
// 621.030 us; speedup vs baseline: 1.1181x; 1.0376x over previous
//
#include <hip/hip_runtime.h>
#include <hip/hip_bf16.h>
#include <math.h>

#define N_NODES 50000
#define N_EDGES 250000
#define BB      128
#define DD      302
#define QQ      600
#define CC      2000
#define NEG_SLOPE 0.2f
#define GS      304        // padded row stride for xb/G/P (16B-aligned bf16 rows)
#define KP      320        // padded K (10 x 32)
#define KSTEPS  10         // KP / 32
#define PC      64         // nodes per pooling chunk
#define BPK_KS  20480      // shorts per k-step in packed B: [hi 320x32][lo 320x32]

typedef __attribute__((ext_vector_type(8))) short short8;
typedef __attribute__((ext_vector_type(4))) float f32x4;

__device__ __forceinline__ void gload_lds16(const void* g, void* l) {
    __builtin_amdgcn_global_load_lds((const __attribute__((address_space(1))) void*)g,
                                     (__attribute__((address_space(3))) void*)l, 16, 0, 0);
}

// bank-spread slot for packed B: 2 lanes/bank on ds_read_b128 (free per m136)
__device__ __host__ __forceinline__ int bswz(int q, int n) {
    return q ^ (n & 3) ^ ((n >> 2) & 3);
}

__device__ __forceinline__ unsigned short f2bf(float v) {   // round-half-up bf16
    return (unsigned short)((__float_as_uint(v) + 0x8000u) >> 16);
}
__device__ __forceinline__ float bf2f(unsigned short u) {
    return __uint_as_float(((unsigned int)u) << 16);
}

// ---------------------------------------------------------------- CSR build
// deg = pure in-edge histogram; self-loop slot is implicit:
// node n owns esrc slots [offs[n]+partials[n>>8]+n, ... + deg[n]] (deg[n]+1 slots).
__global__ void k_zero_dc(int* deg, int* cursor) {
    int i = blockIdx.x * 256 + threadIdx.x;
    if (i < N_NODES) { deg[i] = 0; cursor[i] = 0; }
}

__global__ void k_histogram(const int* __restrict__ dst, int* deg) {
    int e = blockIdx.x * blockDim.x + threadIdx.x;
    if (e < N_EDGES) atomicAdd(&deg[dst[e]], 1);
}

__global__ void k_scan_block(const int* __restrict__ deg, int* offs, int* partials) {
    __shared__ int sh[256];
    int i = blockIdx.x * 256 + threadIdx.x;
    int v = (i < N_NODES) ? deg[i] : 0;
    sh[threadIdx.x] = v;
    __syncthreads();
    for (int d = 1; d < 256; d <<= 1) {
        int t = (threadIdx.x >= d) ? sh[threadIdx.x - d] : 0;
        __syncthreads();
        sh[threadIdx.x] += t;
        __syncthreads();
    }
    if (i < N_NODES) offs[i] = sh[threadIdx.x] - v;   // exclusive (block-local)
    if (threadIdx.x == 255) partials[blockIdx.x] = sh[255];
}

__global__ void k_scan_partials(int* partials, int nb) {
    __shared__ int sh[256];
    int v = (threadIdx.x < nb) ? partials[threadIdx.x] : 0;
    sh[threadIdx.x] = v;
    __syncthreads();
    for (int d = 1; d < 256; d <<= 1) {
        int t = (threadIdx.x >= d) ? sh[threadIdx.x - d] : 0;
        __syncthreads();
        sh[threadIdx.x] += t;
        __syncthreads();
    }
    if (threadIdx.x < nb) partials[threadIdx.x] = sh[threadIdx.x] - v;  // exclusive
}

__global__ void k_scatter(const int* __restrict__ src, const int* __restrict__ dst,
                          const int* __restrict__ offs, const int* __restrict__ partials,
                          const int* __restrict__ deg, int* cursor, int* esrc) {
    int i = blockIdx.x * blockDim.x + threadIdx.x;
    if (i < N_EDGES) {
        int d = dst[i];
        int base = offs[d] + partials[d >> 8] + d;
        int pos = base + atomicAdd(&cursor[d], 1);
        esrc[pos] = src[i];
    } else if (i < N_EDGES + N_NODES) {
        int n = i - N_EDGES;
        int base = offs[n] + partials[n >> 8] + n;
        esrc[base + deg[n]] = n;   // self loop in the last slot (deg final before this kernel)
    }
}

// ---------------------------------------------------------------- x -> bf16 padded [N][GS]
__global__ __launch_bounds__(256) void k_xcast(const float* __restrict__ x,
                                               unsigned short* __restrict__ xb) {
    int idx = blockIdx.x * 256 + threadIdx.x;      // one thread per 8 bf16 outputs
    const int total = N_NODES * (GS / 8);          // 50000*38
    if (idx >= total) return;
    int row = idx / (GS / 8);
    int c0  = (idx % (GS / 8)) * 8;
    const float* src = x + (size_t)row * DD;
    short8 v;
    #pragma unroll
    for (int p = 0; p < 8; p++) {
        int c = c0 + p;
        v[p] = (c < DD) ? (short)f2bf(src[c]) : (short)0;
    }
    *(short8*)(xb + (size_t)row * GS + c0) = v;
}

// ---------------------------------------------------------------- theta pack + attvec rows + qp (one dispatch)
__global__ void k_theta_qp(const float* __restrict__ theta,
                           const float* __restrict__ att_src,
                           const float* __restrict__ att_dst,
                           unsigned short* __restrict__ bpk,
                           const float* __restrict__ query,
                           const float* __restrict__ attW,
                           float* __restrict__ qp) {
    if (blockIdx.x >= 402) {                          // ---- qp branch
        int t = blockIdx.x - 402;                     // 0..255
        int b = t >> 1;
        int d = (t & 1) * 256 + threadIdx.x;
        if (d >= DD) return;
        const float* qrow = query + (size_t)b * QQ;
        float acc = 0.f;
        #pragma unroll 8
        for (int q = 0; q < QQ; q++) acc += qrow[q] * attW[(size_t)q * DD + d];
        qp[(size_t)b * DD + d] = acc;
        return;
    }
    if (blockIdx.x >= 400) {
        int k = (blockIdx.x - 400) * 256 + threadIdx.x;
        if (k >= KP) return;
        float vs = 0.f, vd = 0.f;
        if (k < DD) {
            for (int j = 0; j < DD; j++) {
                float t = theta[j * DD + k];
                vs += t * att_src[j];
                vd += t * att_dst[j];
            }
        }
        int ks = k >> 5, kk = k & 31, q = kk >> 3, kb = kk & 7;
        size_t b0 = (size_t)ks * BPK_KS + DD * 32 + bswz(q, DD) * 8 + kb;
        size_t b1 = (size_t)ks * BPK_KS + (DD + 1) * 32 + bswz(q, DD + 1) * 8 + kb;
        unsigned int u, uh, ul;
        u  = __float_as_uint(vs);
        uh = (u + 0x8000u) & 0xffff0000u;
        ul = (__float_as_uint(vs - __uint_as_float(uh)) + 0x8000u) >> 16;
        bpk[b0]         = (unsigned short)(uh >> 16);
        bpk[b0 + 10240] = (unsigned short)ul;
        u  = __float_as_uint(vd);
        uh = (u + 0x8000u) & 0xffff0000u;
        ul = (__float_as_uint(vd - __uint_as_float(uh)) + 0x8000u) >> 16;
        bpk[b1]         = (unsigned short)(uh >> 16);
        bpk[b1 + 10240] = (unsigned short)ul;
        return;
    }
    int idx = blockIdx.x * 256 + threadIdx.x;
    if (idx >= KP * KP) return;
    int n = idx / KP, k = idx % KP;
    if (n == DD || n == DD + 1) return;
    float v = (n < DD && k < DD) ? theta[n * DD + k] : 0.f;
    unsigned int u  = __float_as_uint(v);
    unsigned int uh = (u + 0x8000u) & 0xffff0000u;    // round-half-up bf16
    float hf = __uint_as_float(uh);
    float lo = v - hf;
    unsigned int ul = (__float_as_uint(lo) + 0x8000u) >> 16;
    int ks = k >> 5, kk = k & 31, q = kk >> 3, kb = kk & 7;
    size_t base = (size_t)ks * BPK_KS + n * 32 + bswz(q, n) * 8 + kb;
    bpk[base]         = (unsigned short)(uh >> 16);
    bpk[base + 10240] = (unsigned short)ul;
}

// ---------------------------------------------------------------- MFMA GEMM: bf16 A (all 3 layers)
// A rows are bf16 [*][GS] with zero pads (xb for layer 1, Pb after).
// lo(A)==0 by construction -> 2 MFMA passes (A*Bhi + A*Blo), no convert
// chain, 16B A-loads.  Single MFMA kernel in module (tight regalloc).
__global__ __launch_bounds__(256) void k_mfma_gemm16(const unsigned short* __restrict__ A,
                                                     const unsigned short* __restrict__ Bpk,
                                                     unsigned short* __restrict__ Gb,
                                                     float* __restrict__ a_s,
                                                     float* __restrict__ a_d, int M) {
    __shared__ __attribute__((aligned(16))) unsigned short Bs[2][BPK_KS]; // 80KB

    const int tid   = threadIdx.x;
    const int lane  = tid & 63;
    const int wave  = tid >> 6;         // 0..3
    const int q     = lane >> 4;        // 0..3
    const int mr    = lane & 15;
    const int m0    = blockIdx.x * 64;
    const int nbase = wave * 80;

    f32x4 acc[4][5];
    #pragma unroll
    for (int i = 0; i < 4; i++)
        #pragma unroll
        for (int j = 0; j < 5; j++)
            acc[i][j] = (f32x4){0.f, 0.f, 0.f, 0.f};

    const unsigned short* arow[4];
    bool rok[4];
    #pragma unroll
    for (int mt = 0; mt < 4; mt++) {
        int row = m0 + mt * 16 + mr;
        rok[mt] = row < M;
        arow[mt] = A + (size_t)(row < M ? row : 0) * GS;
    }

    const char* gB = (const char*)Bpk;

    auto loadA = [&](short8 (&s)[4], int ks) {
        const int k0c = ks * 32 + q * 8;
        #pragma unroll
        for (int mt = 0; mt < 4; mt++) {
            if (rok[mt] && (k0c + 8 <= GS)) {        // rows: 304 shorts, pads zero
                s[mt] = *(const short8*)(arow[mt] + k0c);
            } else {
                s[mt] = (short8){0,0,0,0,0,0,0,0};   // k >= 304: zero (B pads also zero)
            }
        }
    };

    auto stageB = [&](int buf, int ks) {
        const char* gsrc = gB + (size_t)(ks * BPK_KS) * 2;
        #pragma unroll
        for (int j = 0; j < 10; j++) {
            int chunk = j * 4 + wave;                 // 0..39, wave-uniform base
            gload_lds16(gsrc + chunk * 1024 + lane * 16,
                        (char*)Bs[buf] + chunk * 1024);
        }
    };

    short8 scur[4], snext[4];

    loadA(scur, 0);
    stageB(0, 0);
    __syncthreads();

    #pragma unroll
    for (int ks = 0; ks < KSTEPS; ks++) {
        if (ks + 1 < KSTEPS) {
            stageB((ks + 1) & 1, ks + 1);
            loadA(snext, ks + 1);
        }

        const unsigned short* Bc = Bs[ks & 1];
        short8 bh[5], bl[5];
        #pragma unroll
        for (int nt = 0; nt < 5; nt++) {
            int col = nbase + nt * 16 + mr;
            int off = col * 32 + bswz(q, col) * 8;
            bh[nt] = *(const short8*)&Bc[off];
            bl[nt] = *(const short8*)&Bc[10240 + off];
        }
        #pragma unroll
        for (int nt = 0; nt < 5; nt++) {
            #pragma unroll
            for (int mt = 0; mt < 4; mt++) {
                acc[mt][nt] = __builtin_amdgcn_mfma_f32_16x16x32_bf16(scur[mt], bh[nt], acc[mt][nt], 0, 0, 0);
                acc[mt][nt] = __builtin_amdgcn_mfma_f32_16x16x32_bf16(scur[mt], bl[nt], acc[mt][nt], 0, 0, 0);
            }
        }

        __syncthreads();

        #pragma unroll
        for (int mt = 0; mt < 4; mt++) scur[mt] = snext[mt];
    }

    #pragma unroll
    for (int mt = 0; mt < 4; mt++) {
        int row_b = m0 + mt * 16 + q * 4;
        #pragma unroll
        for (int nt = 0; nt < 5; nt++) {
            int col = nbase + nt * 16 + mr;
            if (col > DD + 1) continue;
            #pragma unroll
            for (int r = 0; r < 4; r++) {
                int row = row_b + r;
                if (row >= M) continue;
                float v = acc[mt][nt][r];
                if (col < DD) {
                    Gb[(size_t)row * GS + col] = f2bf(v);
                } else if (col == DD) {
                    a_s[row] = v;
                    Gb[(size_t)row * GS + DD] = 0;
                } else {
                    a_d[row] = v;
                    Gb[(size_t)row * GS + DD + 1] = 0;
                }
            }
        }
    }
}

// ---------------------------------------------------------------- tiled SGEMM (final linear)
#define BM 64
#define BN 64
#define BK 16
__global__ __launch_bounds__(256) void k_gemm_nt(const float* __restrict__ A,
                                                 const float* __restrict__ B,
                                                 float* __restrict__ C,
                                                 int M, int N, int K,
                                                 const float* __restrict__ bias,
                                                 int relu_a) {
    __shared__ float As[BK][BM + 4];
    __shared__ float Bs[BK][BN + 4];
    int m0 = blockIdx.y * BM;
    int n0 = blockIdx.x * BN;
    int tid = threadIdx.x;
    int tr = tid >> 4;
    int tc = tid & 15;
    float acc[4][4] = {};
    for (int k0 = 0; k0 < K; k0 += BK) {
        #pragma unroll
        for (int j = 0; j < 4; j++) {
            int e = tid + 256 * j;
            int r = e >> 4;
            int k = e & 15;
            int gk = k0 + k;
            int gm = m0 + r;
            float va = 0.f;
            if (gm < M && gk < K) va = A[(size_t)gm * K + gk];
            if (relu_a) va = fmaxf(va, 0.f);
            As[k][r] = va;
            int gn = n0 + r;
            float vb = 0.f;
            if (gn < N && gk < K) vb = B[(size_t)gn * K + gk];
            Bs[k][r] = vb;
        }
        __syncthreads();
        #pragma unroll
        for (int k = 0; k < BK; k++) {
            float a[4], b[4];
            #pragma unroll
            for (int i = 0; i < 4; i++) a[i] = As[k][tr * 4 + i];
            #pragma unroll
            for (int j = 0; j < 4; j++) b[j] = Bs[k][tc * 4 + j];
            #pragma unroll
            for (int i = 0; i < 4; i++)
                #pragma unroll
                for (int j = 0; j < 4; j++)
                    acc[i][j] += a[i] * b[j];
        }
        __syncthreads();
    }
    #pragma unroll
    for (int i = 0; i < 4; i++) {
        int gm = m0 + tr * 4 + i;
        if (gm >= M) continue;
        #pragma unroll
        for (int j = 0; j < 4; j++) {
            int gn = n0 + tc * 4 + j;
            if (gn < N) {
                float v = acc[i][j];
                if (bias) v += bias[gn];
                C[(size_t)gm * N + gn] = v;
            }
        }
    }
}

// ---------------------------------------------------------------- softmax-aggregate (wave / dst node)
// Lane-parallel edge precompute + __shfl broadcast gather (R10, verified).
// Output P stored BF16 (halves the write; next GEMM consumes bf16 A).
__global__ __launch_bounds__(256) void k_aggregate(const unsigned short* __restrict__ Gb,
                                                   const float* __restrict__ a_s,
                                                   const float* __restrict__ a_d,
                                                   const int* __restrict__ offs,
                                                   const int* __restrict__ partials,
                                                   const int* __restrict__ deg,
                                                   const int* __restrict__ esrc,
                                                   const float* __restrict__ bias,
                                                   unsigned short* __restrict__ Pb,
                                                   const float* __restrict__ qp,
                                                   const int* __restrict__ batch,
                                                   float* __restrict__ sarr) {
    int gid = blockIdx.x * blockDim.x + threadIdx.x;
    int n = gid >> 6, lane = gid & 63;
    if (n >= N_NODES) return;
    int beg = offs[n] + partials[n >> 8] + n;
    int cnt = deg[n] + 1;
    float adn = a_d[n];

    // ---- lane-parallel first chunk: lane i owns edge i
    int   s_reg = 0;
    float e_reg = -1.0e30f;
    float m = -1.0e30f, den = 0.f;
    if (lane < cnt) {
        s_reg = esrc[beg + lane];
        float e = a_s[s_reg] + adn;
        e = (e > 0.f) ? e : NEG_SLOPE * e;
        e_reg = e;
        m = e; den = 1.f;                 // exp(e-e)=1
    }
    // rare extra chunks: online accumulate
    for (int i = 64 + lane; i < cnt; i += 64) {
        float e = a_s[esrc[beg + i]] + adn;
        e = (e > 0.f) ? e : NEG_SLOPE * e;
        float nm = fmaxf(m, e);
        den = den * __expf(m - nm) + __expf(e - nm);
        m = nm;
    }
    // butterfly combine (finite sentinel keeps exp args finite)
    for (int off = 32; off; off >>= 1) {
        float mo = __shfl_xor(m, off);
        float dn = __shfl_xor(den, off);
        float nm = fmaxf(m, mo);
        den = den * __expf(m - nm) + dn * __expf(mo - nm);
        m = nm;
    }
    float inv_den = 1.f / den;
    float w_reg = __expf(e_reg - m) * inv_den;   // valid for lane < min(cnt,64)

    const int c0 = lane * 8;            // 8 bf16 cols per lane; lanes 0..37 active
    const bool act = c0 < GS;
    float A8[8] = {0.f,0.f,0.f,0.f,0.f,0.f,0.f,0.f};
    const int nfirst = (cnt < 64) ? cnt : 64;
    #pragma unroll 4
    for (int j = 0; j < nfirst; j++) {
        int   s = __shfl(s_reg, j);      // register broadcast — no memory dep
        float w = __shfl(w_reg, j);
        if (act) {
            int4 v = *(const int4*)(Gb + (size_t)s * GS + c0);
            unsigned int u0 = (unsigned int)v.x, u1 = (unsigned int)v.y;
            unsigned int u2 = (unsigned int)v.z, u3 = (unsigned int)v.w;
            A8[0] += w * __uint_as_float(u0 << 16);
            A8[1] += w * __uint_as_float(u0 & 0xffff0000u);
            A8[2] += w * __uint_as_float(u1 << 16);
            A8[3] += w * __uint_as_float(u1 & 0xffff0000u);
            A8[4] += w * __uint_as_float(u2 << 16);
            A8[5] += w * __uint_as_float(u2 & 0xffff0000u);
            A8[6] += w * __uint_as_float(u3 << 16);
            A8[7] += w * __uint_as_float(u3 & 0xffff0000u);
        }
    }
    // rare overflow edges: serial recompute path
    for (int i = 64; i < cnt; i++) {
        int s = esrc[beg + i];
        float e = a_s[s] + adn;
        e = (e > 0.f) ? e : NEG_SLOPE * e;
        float w = __expf(e - m) * inv_den;
        if (act) {
            int4 v = *(const int4*)(Gb + (size_t)s * GS + c0);
            unsigned int u0 = (unsigned int)v.x, u1 = (unsigned int)v.y;
            unsigned int u2 = (unsigned int)v.z, u3 = (unsigned int)v.w;
            A8[0] += w * __uint_as_float(u0 << 16);
            A8[1] += w * __uint_as_float(u0 & 0xffff0000u);
            A8[2] += w * __uint_as_float(u1 << 16);
            A8[3] += w * __uint_as_float(u1 & 0xffff0000u);
            A8[4] += w * __uint_as_float(u2 << 16);
            A8[5] += w * __uint_as_float(u2 & 0xffff0000u);
            A8[6] += w * __uint_as_float(u3 << 16);
            A8[7] += w * __uint_as_float(u3 & 0xffff0000u);
        }
    }

    // ---- bias + ReLU + write P (bf16); pads 302/303 -> 0
    float o[8];
    if (act) {
        short8 wv;
        #pragma unroll
        for (int p = 0; p < 8; p++) {
            int col = c0 + p;
            float b = (col < DD) ? bias[col] : 0.f;
            o[p] = (col < DD) ? fmaxf(A8[p] + b, 0.f) : 0.f;
            wv[p] = (short)f2bf(o[p]);
        }
        *(short8*)(Pb + (size_t)n * GS + c0) = wv;
    }

    // ---- fused pooling score (layer 3 only)
    if (sarr) {
        float d = 0.f;
        if (act) {
            const float* qv = qp + (size_t)batch[n] * DD;
            #pragma unroll
            for (int p = 0; p < 8; p++) {
                int col = c0 + p;
                if (col < DD) d += o[p] * qv[col];
            }
        }
        for (int off = 32; off; off >>= 1) d += __shfl_xor(d, off);
        if (lane == 0) sarr[n] = d * 0.04082482904638630f;   // 1/sqrt(600)
    }
}

// ---------------------------------------------------------------- pooling pieces
// per-graph softmax stats; fused: inline bounds search, writes wn, zeros pooled[b]
__global__ __launch_bounds__(256) void k_gstats(const float* __restrict__ sarr,
                                                const int* __restrict__ batch,
                                                float* __restrict__ wn,
                                                float* __restrict__ pooled) {
    int b = blockIdx.x;
    int lo = 0, hi = N_NODES;
    while (lo < hi) { int mid = (lo + hi) >> 1; if (batch[mid] < b) lo = mid + 1; else hi = mid; }
    int beg = lo;
    hi = N_NODES;
    while (lo < hi) { int mid = (lo + hi) >> 1; if (batch[mid] < b + 1) lo = mid + 1; else hi = mid; }
    int cnt = lo - beg;

    __shared__ float red[256];
    float m = -INFINITY;
    for (int i = threadIdx.x; i < cnt; i += 256) m = fmaxf(m, sarr[beg + i]);
    red[threadIdx.x] = m;
    __syncthreads();
    for (int d = 128; d; d >>= 1) {
        if (threadIdx.x < d) red[threadIdx.x] = fmaxf(red[threadIdx.x], red[threadIdx.x + d]);
        __syncthreads();
    }
    m = red[0];
    __syncthreads();
    float den = 0.f;
    for (int i = threadIdx.x; i < cnt; i += 256) den += __expf(sarr[beg + i] - m);
    red[threadIdx.x] = den;
    __syncthreads();
    for (int d = 128; d; d >>= 1) {
        if (threadIdx.x < d) red[threadIdx.x] += red[threadIdx.x + d];
        __syncthreads();
    }
    float dinv = (cnt > 0) ? 1.f / red[0] : 0.f;
    for (int i = threadIdx.x; i < cnt; i += 256)
        wn[beg + i] = __expf(sarr[beg + i] - m) * dinv;
    for (int j = threadIdx.x; j < DD; j += 256)
        pooled[(size_t)b * DD + j] = 0.f;
}

// node-chunk-parallel weighted segment sum over bf16 P (batch sorted)
__global__ __launch_bounds__(256) void k_poolacc(const unsigned short* __restrict__ Pb,
                                                 const float* __restrict__ wn,
                                                 const int* __restrict__ batch,
                                                 float* __restrict__ pooled) {
    int c0 = blockIdx.x * PC;
    if (c0 >= N_NODES) return;
    int nmax = N_NODES - c0; if (nmax > PC) nmax = PC;
    __shared__ int   sb[PC];
    __shared__ float sw[PC];
    for (int i = threadIdx.x; i < nmax; i += 256) {
        sb[i] = batch[c0 + i];
        sw[i] = wn[c0 + i];
    }
    __syncthreads();
    int f0 = threadIdx.x, f1 = threadIdx.x + 256;
    float a0 = 0.f, a1 = 0.f;
    int g = sb[0];
    for (int i = 0; i < nmax; i++) {
        int bi = sb[i];
        if (bi != g) {                       // wave-uniform branch
            if (f0 < DD) atomicAdd(&pooled[(size_t)g * DD + f0], a0);
            if (f1 < DD) atomicAdd(&pooled[(size_t)g * DD + f1], a1);
            a0 = 0.f; a1 = 0.f; g = bi;
        }
        float w = sw[i];
        const unsigned short* row = Pb + (size_t)(c0 + i) * GS;
        if (f0 < DD) a0 += w * bf2f(row[f0]);
        if (f1 < DD) a1 += w * bf2f(row[f1]);
    }
    if (f0 < DD) atomicAdd(&pooled[(size_t)g * DD + f0], a0);
    if (f1 < DD) atomicAdd(&pooled[(size_t)g * DD + f1], a1);
}

// ---------------------------------------------------------------- launch
extern "C" void kernel_launch(void* const* d_in, const int* in_sizes, int n_in,
                              void* d_out, int out_size, void* d_ws, size_t ws_size,
                              hipStream_t stream) {
    const float* x        = (const float*)d_in[0];
    const int*   edges    = (const int*)d_in[1];   // [2, E]
    const float* query    = (const float*)d_in[2];
    const int*   batch    = (const int*)d_in[3];
    const float* theta    = (const float*)d_in[4];
    const float* att_src  = (const float*)d_in[5];
    const float* att_dst  = (const float*)d_in[6];
    const float* gat_bias = (const float*)d_in[7];
    const float* attW     = (const float*)d_in[8];
    const float* lin_w    = (const float*)d_in[9];
    const float* lin_b    = (const float*)d_in[10];
    float* out = (float*)d_out;

    char* ws = (char*)d_ws;
    size_t off = 0;
    auto alloc = [&](size_t bytes) -> void* {
        off = (off + 255) & ~(size_t)255;
        void* p = ws + off;
        off += bytes;
        return p;
    };

    unsigned short* xb = (unsigned short*)alloc((size_t)N_NODES * GS * 2);  // x in bf16 (padded)
    unsigned short* Gb = (unsigned short*)alloc((size_t)N_NODES * GS * 2);  // gemm output (bf16)
    unsigned short* Pb = (unsigned short*)alloc((size_t)N_NODES * GS * 2);  // layer output (bf16)
    unsigned short* bpk = (unsigned short*)alloc((size_t)KSTEPS * BPK_KS * 2); // packed B, 409.6KB
    float* a_s  = (float*)alloc((size_t)N_NODES * 4);
    float* a_d  = (float*)alloc((size_t)N_NODES * 4);
    float* sarr = (float*)alloc((size_t)N_NODES * 4);
    float* wn   = (float*)alloc((size_t)N_NODES * 4);
    int* deg    = (int*)alloc((size_t)N_NODES * 4);
    int* cursor = (int*)alloc((size_t)N_NODES * 4);
    int* offs   = (int*)alloc((size_t)N_NODES * 4);
    int* esrc   = (int*)alloc((size_t)(N_EDGES + N_NODES) * 4);
    int* partials = (int*)alloc(256 * 4);
    float* qp   = (float*)alloc((size_t)BB * DD * 4);
    float* pooled = (float*)alloc((size_t)BB * DD * 4);

    const int* e_src = edges;
    const int* e_dst = edges + N_EDGES;

    const int NB_SCAN = (N_NODES + 255) / 256;   // 196

    // ---- CSR build (deg/cursor zeroed via kernel; self-loop slot implicit)
    k_zero_dc<<<NB_SCAN, 256, 0, stream>>>(deg, cursor);
    k_histogram<<<(N_EDGES + 255) / 256, 256, 0, stream>>>(e_dst, deg);
    k_scan_block<<<NB_SCAN, 256, 0, stream>>>(deg, offs, partials);
    k_scan_partials<<<1, 256, 0, stream>>>(partials, NB_SCAN);
    k_scatter<<<(N_EDGES + N_NODES + 255) / 256, 256, 0, stream>>>(e_src, e_dst, offs, partials, deg, cursor, esrc);

    // ---- x -> bf16 padded; theta pack + attvec + qp
    k_xcast<<<(N_NODES * (GS / 8) + 255) / 256, 256, 0, stream>>>(x, xb);
    k_theta_qp<<<658, 256, 0, stream>>>(theta, att_src, att_dst, bpk, query, attW, qp);

    // ---- 3 GAT layers (single lean bf16-A GEMM for all; layer 3 fuses scores)
    int mfma_blocks = (N_NODES + 63) / 64;   // 782
    int wave_blocks = (N_NODES + 3) / 4;
    for (int layer = 0; layer < 3; layer++) {
        k_mfma_gemm16<<<mfma_blocks, 256, 0, stream>>>(layer == 0 ? xb : Pb, bpk, Gb, a_s, a_d, N_NODES);
        bool last = (layer == 2);
        k_aggregate<<<wave_blocks, 256, 0, stream>>>(Gb, a_s, a_d, offs, partials, deg, esrc, gat_bias, Pb,
                                                     last ? qp : (const float*)nullptr,
                                                     last ? batch : (const int*)nullptr,
                                                     last ? sarr : (float*)nullptr);
    }

    // ---- attention pooling + classifier
    k_gstats<<<BB, 256, 0, stream>>>(sarr, batch, wn, pooled);
    k_poolacc<<<(N_NODES + PC - 1) / PC, 256, 0, stream>>>(Pb, wn, batch, pooled);
    {
        dim3 g((CC + BN - 1) / BN, (BB + BM - 1) / BM);
        k_gemm_nt<<<g, 256, 0, stream>>>(pooled, lin_w, out, BB, CC, DD, lin_b, 1);
    }
}